// Round 1
// baseline (166.694 us; speedup 1.0000x reference)
//
#include <hip/hip_runtime.h>

// Sinkhorn fixed-point iteration for fermionic canonical ensembles.
// B=2048 systems, P=64 orbitals, N_PART=32, n_iters=20 (read from d_in[2]).
// One wave (64 lanes) per batch element; lane = orbital p for per-orbital
// work; the sequential Q recursion is computed redundantly by all lanes in
// registers (fully unrolled => compile-time indices => no LDS round-trips).

#define NPART 32
#define PORB  64

__device__ __forceinline__ float fastrcp(float x) {
    return __builtin_amdgcn_rcpf(x);   // v_rcp_f32, ~1 ulp; tolerance is 2e-2
}

__global__ __launch_bounds__(PORB, 1) void sinkhorn_kernel(
    const float* __restrict__ n_in,
    const float* __restrict__ beta_ptr,
    const int*   __restrict__ iters_ptr,
    float*       __restrict__ out)
{
    const int b    = blockIdx.x;
    const int lane = threadIdx.x;      // orbital index p
    const float beta    = beta_ptr[0];
    const int   n_iters = iters_ptr[0];

    __shared__ float t_sh[PORB];   // t_p = -beta*eps_p, staged per iteration
    __shared__ float c_sh[NPART];  // C_{k+1} broadcast

    const float n_p = n_in[b * PORB + lane];

    // ---- one-time per system: nn, sum(nn), eps0 ----
    float s = n_p;
    #pragma unroll
    for (int off = 32; off >= 1; off >>= 1) s += __shfl_xor(s, off);

    const float nn = n_p * ((float)NPART / s);

    float snn = nn;
    #pragma unroll
    for (int off = 32; off >= 1; off >>= 1) snn += __shfl_xor(snn, off);
    const float inv_snn  = fastrcp(snn);
    const float ratio_nn = nn * fastrcp(1.0f - nn);  // nn/(1-nn)
    const float inv_beta = fastrcp(beta);

    float eps = -__logf(ratio_nn) * inv_beta;        // eps_GC_guess

    // C_k mapping: lane -> (k = kid+1 in [1,32], half in {0,1})
    const int   kid  = lane & 31;
    const int   half = lane >> 5;
    const float kf   = (float)(kid + 1);

    for (int it = 0; it < n_iters; ++it) {
        const float t = -beta * eps;
        __syncthreads();               // t_sh reuse hazard vs prev iteration
        t_sh[lane] = t;
        __syncthreads();

        // ---- C_{k+1} = sum_p exp(-(k+1)*beta*eps_p), split across halves ----
        float acc = 0.0f;
        #pragma unroll
        for (int j = 0; j < 32; ++j) {
            acc += __expf(kf * t_sh[half * 32 + j]);   // LDS broadcast read
        }
        acc += __shfl_xor(acc, 32);    // merge the two 32-orbital half-sums
        c_sh[kid] = acc;               // both halves write identical value
        __syncthreads();

        // ---- all lanes load C into registers (broadcast reads) ----
        float Cv[NPART];               // Cv[k] = C_{k+1}
        #pragma unroll
        for (int k = 0; k < NPART; ++k) Cv[k] = c_sh[k];

        // E[k] = C[k+1]/C[k] for k=1..31  (E[0] never used by inner loop)
        float E[NPART];
        #pragma unroll
        for (int k = 1; k < NPART; ++k) E[k] = Cv[k] * fastrcp(Cv[k - 1]);

        // ---- Q recursion (sequential in M; fully unrolled, in registers) ----
        const float c1 = Cv[0];
        float invQ[NPART];
        invQ[0] = fastrcp(c1);         // Q[0] = C[1]
        #pragma unroll
        for (int M = 2; M <= NPART; ++M) {
            float prev = 1.0f;
            #pragma unroll
            for (int kk = 1; kk <= M - 1; ++kk) {
                // prev = 1 - E[M-kk]/Q[kk-1] * prev  (compile-time indices)
                prev = 1.0f - (E[M - kk] * invQ[kk - 1]) * prev;
            }
            const float QM = c1 * prev * (1.0f / (float)M);
            invQ[M - 1] = fastrcp(QM);
        }

        // ---- aux partition: per-orbital 32-step recursion ----
        const float x = __expf(t);     // exp(-beta*eps_p)
        float prev = 1.0f;
        float y_nm2 = 0.0f;
        #pragma unroll
        for (int k = 0; k < NPART; ++k) {
            prev = 1.0f - (x * invQ[k]) * prev;
            if (k == NPART - 2) y_nm2 = prev;
        }
        const float Qp1 = prev;                      // ys[N-1]
        const float Qp0 = y_nm2 * invQ[NPART - 1];   // ys[N-2]/Q[N-1]

        // ---- update + normalize: sum_p nn_p eps_p = 0 ----
        const float eps_new = -__logf(ratio_nn * Qp1 * fastrcp(Qp0)) * inv_beta;

        float wsum = nn * eps_new;
        #pragma unroll
        for (int off = 32; off >= 1; off >>= 1) wsum += __shfl_xor(wsum, off);

        eps = eps_new - wsum * inv_snn;
    }

    out[b * PORB + lane] = eps;
}

extern "C" void kernel_launch(void* const* d_in, const int* in_sizes, int n_in,
                              void* d_out, int out_size, void* d_ws, size_t ws_size,
                              hipStream_t stream) {
    const float* n_ptr    = (const float*)d_in[0];
    const float* beta_ptr = (const float*)d_in[1];
    const int*   it_ptr   = (const int*)d_in[2];
    float*       out      = (float*)d_out;

    const int B = in_sizes[0] / PORB;   // 2048 systems
    sinkhorn_kernel<<<B, PORB, 0, stream>>>(n_ptr, beta_ptr, it_ptr, out);
}